// Round 1
// baseline (2364.350 us; speedup 1.0000x reference)
//
#include <hip/hip_runtime.h>
#include <math.h>

#define NSTATE 1024
#define NPART  32
#define ADIM   20
#define ODIM   64
#define HID    256
#define KIN    84      // ODIM + ADIM
#define NSTEPS 5
#define LRC    0.1f

#define FMA8(av, wa, wb, accr) do { \
    (accr)[0] += (av)*(wa).x; (accr)[1] += (av)*(wa).y; \
    (accr)[2] += (av)*(wa).z; (accr)[3] += (av)*(wa).w; \
    (accr)[4] += (av)*(wb).x; (accr)[5] += (av)*(wb).y; \
    (accr)[6] += (av)*(wb).z; (accr)[7] += (av)*(wb).w; } while (0)

// One block per state: 32 particles' full 5-step SVGD recurrence lives in LDS.
// Selection (argmin of q1/q2) is folded into the relu bit-masks, so backward is
// two clean GEMMs per step with zero rows for the losing net.
__global__ void __launch_bounds__(256, 2)
svgd_fused(const float* __restrict__ obs,  const float* __restrict__ a0g,
           const float* __restrict__ w1a,  const float* __restrict__ b1a,
           const float* __restrict__ w2a,  const float* __restrict__ b2a,
           const float* __restrict__ w3a,  const float* __restrict__ b3a,
           const float* __restrict__ w1b,  const float* __restrict__ b1b,
           const float* __restrict__ w2b,  const float* __restrict__ b2b,
           const float* __restrict__ w3b,  const float* __restrict__ b3b,
           float* __restrict__ out)
{
    __shared__ __align__(16) float A0s[NPART*KIN + 16];   // [32][84] = obs|X, + slack for K-pad reads
    __shared__ __align__(16) float buf[NPART*260];        // h1 / g1, stride 260 (bank-stagger)
    __shared__ __align__(16) float Wst[16*256];           // W K-tile; RBF phase: sort|Spair|phi
    __shared__ unsigned int maskb[2][2][NPART][8];        // [net][layer][row][bitword]
    __shared__ float bv[2][2][HID];
    __shared__ float w3s[2][HID];
    __shared__ float Kmat[NPART*NPART];                   // fwd phase: q partials
    __shared__ float d2s[NPART*NPART];
    __shared__ float qv[2][NPART];
    __shared__ float logps[NPART];
    __shared__ float scoreS[NPART*ADIM];
    __shared__ float gsh;

    const int t  = threadIdx.x;
    const int b  = blockIdx.x;
    const int cg = t & 31;     // 32 col-groups of 8 cols
    const int rg = t >> 5;     // 8 row-groups of 4 rows
    const int c0 = cg * 8;
    const int r0 = rg * 4;

    // ---- block-resident loads
    for (int p = t; p < NPART*ODIM; p += 256) {
        int i = p >> 6, d = p & 63;
        A0s[i*KIN + d] = obs[(b*NPART + i)*ODIM + d];
    }
    for (int p = t; p < NPART*ADIM; p += 256) {
        int i = p / ADIM, d = p - i*ADIM;
        A0s[i*KIN + ODIM + d] = a0g[(b*NPART + i)*ADIM + d];
    }
    if (t < 16) A0s[NPART*KIN + t] = 0.f;   // zero the K-pad slack
    bv[0][0][t] = b1a[t]; bv[0][1][t] = b2a[t];
    bv[1][0][t] = b1b[t]; bv[1][1][t] = b2b[t];
    w3s[0][t] = w3a[t];   w3s[1][t] = w3b[t];
    if (t < NPART) logps[t] = 0.f;
    __syncthreads();

    for (int step = 0; step < NSTEPS; ++step) {
        // zero relu bit-masks
        {
            unsigned int* mp = &maskb[0][0][0][0];
            for (int p = t; p < 2*2*NPART*8; p += 256) mp[p] = 0u;
        }
        __syncthreads();

        // ================= forward both nets =================
        for (int net = 0; net < 2; ++net) {
            const float* w1p = net ? w1b : w1a;
            const float* w2p = net ? w2b : w2a;
            const float* b3p = net ? b3b : b3a;

            float acc[4][8];
            #pragma unroll
            for (int rr = 0; rr < 4; ++rr) {
                #pragma unroll
                for (int cc = 0; cc < 8; ++cc) acc[rr][cc] = bv[net][0][c0+cc];
            }
            // z1 = [obs|X] @ w1 + b1   (K=84, zero-padded tiles)
            for (int jt = 0; jt < KIN; jt += 16) {
                __syncthreads();
                #pragma unroll
                for (int i = 0; i < 16; ++i) {
                    int j = jt + i;
                    Wst[i*256 + t] = (j < KIN) ? w1p[j*256 + t] : 0.f;
                }
                __syncthreads();
                #pragma unroll
                for (int j = 0; j < 16; ++j) {
                    float4 wa = *(const float4*)&Wst[j*256 + c0];
                    float4 wb = *(const float4*)&Wst[j*256 + c0 + 4];
                    #pragma unroll
                    for (int rr = 0; rr < 4; ++rr) {
                        float av = A0s[(r0+rr)*KIN + jt + j];
                        FMA8(av, wa, wb, acc[rr]);
                    }
                }
            }
            __syncthreads();
            // h1 = relu(z1) -> buf; sign bits -> mask layer 0
            #pragma unroll
            for (int rr = 0; rr < 4; ++rr) {
                unsigned int bits = 0u; float h[8];
                #pragma unroll
                for (int cc = 0; cc < 8; ++cc) {
                    float v = acc[rr][cc];
                    if (v > 0.f) bits |= (1u << cc);
                    h[cc] = v > 0.f ? v : 0.f;
                }
                *(float4*)&buf[(r0+rr)*260 + c0]     = make_float4(h[0],h[1],h[2],h[3]);
                *(float4*)&buf[(r0+rr)*260 + c0 + 4] = make_float4(h[4],h[5],h[6],h[7]);
                atomicOr(&maskb[net][0][r0+rr][cg>>2], bits << ((cg&3)*8));
            }
            // z2 = h1 @ w2 + b2
            #pragma unroll
            for (int rr = 0; rr < 4; ++rr) {
                #pragma unroll
                for (int cc = 0; cc < 8; ++cc) acc[rr][cc] = bv[net][1][c0+cc];
            }
            for (int jt = 0; jt < HID; jt += 16) {
                __syncthreads();
                #pragma unroll
                for (int i = 0; i < 16; ++i) Wst[i*256 + t] = w2p[(jt+i)*256 + t];
                __syncthreads();
                #pragma unroll
                for (int j = 0; j < 16; ++j) {
                    float4 wa = *(const float4*)&Wst[j*256 + c0];
                    float4 wb = *(const float4*)&Wst[j*256 + c0 + 4];
                    #pragma unroll
                    for (int rr = 0; rr < 4; ++rr) {
                        float av = buf[(r0+rr)*260 + jt + j];
                        FMA8(av, wa, wb, acc[rr]);
                    }
                }
            }
            // q partials + mask layer 1
            #pragma unroll
            for (int rr = 0; rr < 4; ++rr) {
                unsigned int bits = 0u; float qp = 0.f;
                #pragma unroll
                for (int cc = 0; cc < 8; ++cc) {
                    float v = acc[rr][cc];
                    if (v > 0.f) { bits |= (1u << cc); qp += v * w3s[net][c0+cc]; }
                }
                atomicOr(&maskb[net][1][r0+rr][cg>>2], bits << ((cg&3)*8));
                Kmat[(r0+rr)*NPART + cg] = qp;   // Kmat as q-partial scratch
            }
            __syncthreads();
            if (t < NPART) {
                float s = 0.f;
                #pragma unroll
                for (int g = 0; g < NPART; ++g) s += Kmat[t*NPART + g];
                qv[net][t] = s + b3p[0];
            }
            __syncthreads();
        }

        // ======= argmin selection: zero losing net's masks =======
        if (t < NPART) {
            int lose = (qv[0][t] < qv[1][t]) ? 1 : 0;
            #pragma unroll
            for (int w = 0; w < 8; ++w) { maskb[lose][0][t][w] = 0u; maskb[lose][1][t][w] = 0u; }
        }
        __syncthreads();

        // ============ backward both nets, accumulate score ============
        for (int net = 0; net < 2; ++net) {
            const float* w1p = net ? w1b : w1a;
            const float* w2p = net ? w2b : w2a;

            float acc[4][8];
            #pragma unroll
            for (int rr = 0; rr < 4; ++rr) {
                #pragma unroll
                for (int cc = 0; cc < 8; ++cc) acc[rr][cc] = 0.f;
            }
            // dh1[r][n] = sum_k g2[r][k] * w2[n][k]; g2 rebuilt from mask+w3 on the fly
            for (int jt = 0; jt < HID; jt += 16) {
                __syncthreads();
                #pragma unroll
                for (int ii = 0; ii < 4; ++ii) {        // transpose-stage w2: Wst[k][n] = w2[n][k0+k]
                    float4 v = *(const float4*)&w2p[t*256 + jt + ii*4];
                    Wst[(ii*4+0)*256 + t] = v.x;
                    Wst[(ii*4+1)*256 + t] = v.y;
                    Wst[(ii*4+2)*256 + t] = v.z;
                    Wst[(ii*4+3)*256 + t] = v.w;
                }
                __syncthreads();
                unsigned int msh[4];
                #pragma unroll
                for (int rr = 0; rr < 4; ++rr)
                    msh[rr] = maskb[net][1][r0+rr][jt>>5] >> (jt & 31);
                #pragma unroll
                for (int j = 0; j < 16; ++j) {
                    float w3v = w3s[net][jt + j];
                    float4 wa = *(const float4*)&Wst[j*256 + c0];
                    float4 wb = *(const float4*)&Wst[j*256 + c0 + 4];
                    #pragma unroll
                    for (int rr = 0; rr < 4; ++rr) {
                        float av = ((msh[rr] >> j) & 1u) ? w3v : 0.f;
                        FMA8(av, wa, wb, acc[rr]);
                    }
                }
            }
            __syncthreads();
            // g1 = dh1 * relu'(z1) -> buf
            #pragma unroll
            for (int rr = 0; rr < 4; ++rr) {
                unsigned int m1 = maskb[net][0][r0+rr][cg>>2] >> ((cg&3)*8);
                float g[8];
                #pragma unroll
                for (int cc = 0; cc < 8; ++cc)
                    g[cc] = ((m1 >> cc) & 1u) ? acc[rr][cc] : 0.f;
                *(float4*)&buf[(r0+rr)*260 + c0]     = make_float4(g[0],g[1],g[2],g[3]);
                *(float4*)&buf[(r0+rr)*260 + c0 + 4] = make_float4(g[4],g[5],g[6],g[7]);
            }
            __syncthreads();
            // score += g1 @ w1X^T   (w1 rows 64..83 from global, L1/L2-hot)
            {
                int r = t & 31, dg = t >> 5;
                for (int dd = dg; dd < ADIM; dd += 8) {
                    float s = 0.f;
                    for (int j = 0; j < HID; j += 4) {
                        float4 g = *(const float4*)&buf[r*260 + j];
                        float4 w = *(const float4*)&w1p[(ODIM+dd)*256 + j];
                        s += g.x*w.x + g.y*w.y + g.z*w.z + g.w*w.w;
                    }
                    if (net == 0) scoreS[r*ADIM + dd] = s;
                    else          scoreS[r*ADIM + dd] += s;
                }
            }
            __syncthreads();
        }

        // ================= RBF / median / phi / logp =================
        for (int p = t; p < NPART*NPART; p += 256) {
            int i = p >> 5, j = p & 31;
            float s = 0.f;
            #pragma unroll
            for (int d = 0; d < ADIM; ++d) {
                float df = A0s[i*KIN + ODIM + d] - A0s[j*KIN + ODIM + d];
                s += df*df;
            }
            d2s[p] = s;
            Wst[p] = s;   // sort copy
        }
        __syncthreads();
        for (int k = 2; k <= 1024; k <<= 1) {           // bitonic ascending
            for (int jj = k >> 1; jj > 0; jj >>= 1) {
                for (int p = t; p < 1024; p += 256) {
                    int l = p ^ jj;
                    if (l > p) {
                        float x = Wst[p], y = Wst[l];
                        bool up = ((p & k) == 0);
                        if ((x > y) == up) { Wst[p] = y; Wst[l] = x; }
                    }
                }
                __syncthreads();
            }
        }
        if (t == 0) {
            float med  = 0.5f*(Wst[511] + Wst[512]);    // jnp.median of 1024 values
            float sig2 = med / (2.f * logf((float)NPART + 1.f));
            gsh = 1.f / (2.f*sig2 + 1e-8f);
        }
        __syncthreads();
        float gamma = gsh;
        for (int p = t; p < NPART*NPART; p += 256)
            Kmat[p] = expf(-gamma * d2s[p]);
        __syncthreads();

        float* phis  = &Wst[2080];
        float* Spair = &Wst[1024];
        {
            int i = t & 31, dg = t >> 5;
            for (int dd = dg; dd < ADIM; dd += 8) {
                float xi = A0s[i*KIN + ODIM + dd];
                float s = 0.f;
                for (int j = 0; j < NPART; ++j) {
                    float Kij = Kmat[i*NPART + j];
                    s += Kij * (scoreS[j*ADIM + dd] + 2.f*gamma*(xi - A0s[j*KIN + ODIM + dd]));
                }
                phis[i*ADIM + dd] = s * (1.f/NPART);
            }
        }
        for (int p = t; p < NPART*NPART; p += 256) {
            int i = p >> 5, j = p & 31;
            float Kij = Kmat[p];
            float dot = 0.f;
            #pragma unroll
            for (int d = 0; d < ADIM; ++d)
                dot += (A0s[i*KIN + ODIM + d] - A0s[j*KIN + ODIM + d]) * scoreS[j*ADIM + d];
            float c1  = -2.f*gamma*Kij*dot;                                   // term1 contrib
            float inn = 2.f*gamma*Kij*d2s[p] - (float)ADIM*(Kij - (i==j ? 1.f : 0.f));
            Spair[i*33 + j] = c1 - 2.f*gamma*inn;                             // + term2 contrib
        }
        __syncthreads();
        if (t < NPART) {
            float s = 0.f;
            #pragma unroll
            for (int j = 0; j < NPART; ++j) s += Spair[t*33 + j];
            logps[t] -= LRC * (s * (1.f/NPART));
        }
        for (int p = t; p < NPART*ADIM; p += 256) {     // a += LR*phi
            int i = p / ADIM, d = p - i*ADIM;
            A0s[i*KIN + ODIM + d] += LRC * phis[p];
        }
        __syncthreads();
    } // steps

    // ================= epilogue =================
    for (int p = t; p < NPART*ADIM; p += 256) {
        int i = p / ADIM, d = p - i*ADIM;
        out[(b*NPART + i)*ADIM + d] = tanhf(A0s[i*KIN + ODIM + d]);
    }
    if (t < NPART) {
        float lt = 0.f, s0 = 0.f;
        for (int d = 0; d < ADIM; ++d) {
            float a  = A0s[t*KIN + ODIM + d];
            float x  = -2.f*a;
            float sp = fmaxf(x, 0.f) + log1pf(expf(-fabsf(x)));   // softplus(-2a)
            lt -= 2.f*(0.69314718056f - a - sp);
            float v = a0g[(b*NPART + t)*ADIM + d];
            s0 += v*v;
        }
        float lpn = -18.3787706641f - 0.5f*s0;   // -AD/2*log(2*pi*SP0) - 0.5*||a0||^2
        qv[0][t] = lpn + logps[t] + lt;
    }
    __syncthreads();
    if (t == 0) {
        float s = 0.f;
        for (int i = 0; i < NPART; ++i) s += qv[0][i];
        out[NSTATE*NPART*ADIM + b] = s * (1.f/NPART);
    }
}

extern "C" void kernel_launch(void* const* d_in, const int* in_sizes, int n_in,
                              void* d_out, int out_size, void* d_ws, size_t ws_size,
                              hipStream_t stream) {
    svgd_fused<<<NSTATE, 256, 0, stream>>>(
        (const float*)d_in[0],  (const float*)d_in[1],
        (const float*)d_in[2],  (const float*)d_in[3],
        (const float*)d_in[4],  (const float*)d_in[5],
        (const float*)d_in[6],  (const float*)d_in[7],
        (const float*)d_in[8],  (const float*)d_in[9],
        (const float*)d_in[10], (const float*)d_in[11],
        (const float*)d_in[12], (const float*)d_in[13],
        (float*)d_out);
}

// Round 2
// 884.798 us; speedup vs baseline: 2.6722x; 2.6722x over previous
//
#include <hip/hip_runtime.h>
#include <math.h>

#define NPART 32
#define ADIM  20
#define ODIM  64
#define HID   256
#define NSTEPS 5
#define LRC   0.1f

typedef short bf8 __attribute__((ext_vector_type(8)));   // 8 bf16 (4 VGPRs)
typedef float f4  __attribute__((ext_vector_type(4)));   // MFMA C/D

// workspace layout (bf16 element offsets)
#define OW1T(n) ((n)*24576)             // [256 n][96 k]   w1 transposed, k-pad 84->96 (fwd L1 B)
#define OW2T(n) (49152 + (n)*65536)     // [256 n][256 k]  w2 transposed (fwd L2 B)
#define OW2C(n) (180224 + (n)*65536)    // raw w2 copy [h1][z2] (bwd dh1 B: k-contiguous as-is)
#define OW1X(n) (311296 + (n)*8192)     // [32 d][256 n]   w1 rows 64..83, zero-padded (score B)
#define OW3B(n) (327680 + (n)*256)      // w3 bf16
#define WS_ELEMS 328192

__device__ __forceinline__ short f2bf(float x) {          // RNE f32->bf16
    unsigned u = __float_as_uint(x);
    u += 0x7FFFu + ((u >> 16) & 1u);
    return (short)(u >> 16);
}

#define MFMA(a,b,c) __builtin_amdgcn_mfma_f32_16x16x32_bf16((a),(b),(c),0,0,0)

// ---------- prep: build bf16 weight images in ws ----------
__global__ void prep_weights(const float* __restrict__ w1a, const float* __restrict__ w2a,
                             const float* __restrict__ w3a, const float* __restrict__ w1b,
                             const float* __restrict__ w2b, const float* __restrict__ w3b,
                             unsigned short* __restrict__ ws)
{
    int idx = blockIdx.x * 256 + threadIdx.x;
    if (idx >= WS_ELEMS) return;
    float val;
    if (idx < 49152) {                       // w1t[n][k96]
        int net = idx / 24576, rem = idx % 24576;
        int n = rem / 96, k = rem % 96;
        const float* w1 = net ? w1b : w1a;
        val = (k < 84) ? w1[k*256 + n] : 0.f;
    } else if (idx < 180224) {               // w2t[n][k]
        int t2 = idx - 49152; int net = t2 / 65536, rem = t2 % 65536;
        int n = rem / 256, k = rem % 256;
        const float* w2 = net ? w2b : w2a;
        val = w2[k*256 + n];
    } else if (idx < 311296) {               // w2c raw copy
        int t2 = idx - 180224; int net = t2 / 65536, rem = t2 % 65536;
        const float* w2 = net ? w2b : w2a;
        val = w2[rem];
    } else if (idx < 327680) {               // w1x[d32][n]
        int t2 = idx - 311296; int net = t2 / 8192, rem = t2 % 8192;
        int d = rem / 256, n = rem % 256;
        const float* w1 = net ? w1b : w1a;
        val = (d < 20) ? w1[(64 + d)*256 + n] : 0.f;
    } else {                                 // w3 bf16
        int t2 = idx - 327680; int net = t2 / 256, k = t2 % 256;
        const float* w3 = net ? w3b : w3a;
        val = w3[k];
    }
    ws[idx] = (unsigned short)f2bf(val);
}

// ---------- main: one block per state ----------
__global__ void __launch_bounds__(256, 2)
svgd_main(const float* __restrict__ obs,  const float* __restrict__ a0g,
          const float* __restrict__ b1a,  const float* __restrict__ b2a, const float* __restrict__ b3a,
          const float* __restrict__ b1b,  const float* __restrict__ b2b, const float* __restrict__ b3b,
          const float* __restrict__ w3af, const float* __restrict__ w3bf,
          const unsigned short* __restrict__ ws, float* __restrict__ out)
{
    __shared__ short A0s[32*96];          // [obs|X|pad] bf16, stride 96
    __shared__ short h1s[32*264];         // h1 bf16, stride 264 (odd-quad advance for b128 frags)
    __shared__ short g1s[32*264];         // g1 bf16
    __shared__ unsigned maskS[2][2][32][8];  // relu bitmasks [net][layer][row][word]
    __shared__ float Xm[32*20];           // fp32 master particles
    __shared__ float d2s[1024];
    __shared__ float Kms[1024];
    __shared__ float dots[1024];          // dot(diff_ij, score_j)
    __shared__ float Spair[32*33];
    __shared__ float scoreS[32*21];
    __shared__ float phis[32*20];
    __shared__ float qpart[2][4][32];
    __shared__ int   winsS[32];
    __shared__ float logps[32];
    __shared__ unsigned short lutI[496], lutJ[496];
    __shared__ float med2[2];
    __shared__ float qvS[32];

    const int t = threadIdx.x, b = blockIdx.x;
    const int lane = t & 63, wv = t >> 6;
    const int q = lane >> 4, mp = lane & 15;
    const int nb = wv * 64;               // this wave's 64-col slice for the 256-wide GEMMs

    // ---- init ----
    for (int p = t; p < 32*ODIM; p += 256) {
        int i = p >> 6, d = p & 63;
        A0s[i*96 + d] = f2bf(obs[(b*32 + i)*ODIM + d]);
    }
    for (int p = t; p < 640; p += 256) {
        int i = p / 20, d = p - i*20;
        float v = a0g[(b*32 + i)*20 + d];
        Xm[p] = v;
        A0s[i*96 + 64 + d] = f2bf(v);
    }
    for (int p = t; p < 32*12; p += 256) { int i = p/12, d = p - i*12; A0s[i*96 + 84 + d] = 0; }
    if (t < 496) {                        // upper-triangle pair LUT
        int i_ = 0, rem = t;
        while (rem >= 31 - i_) { rem -= 31 - i_; ++i_; }
        lutI[t] = (unsigned short)i_; lutJ[t] = (unsigned short)(i_ + 1 + rem);
    }
    if (t < 32) logps[t] = 0.f;
    __syncthreads();

    for (int step = 0; step < NSTEPS; ++step) {
        { unsigned* mz = &maskS[0][0][0][0];
          for (int p = t; p < 2*2*32*8; p += 256) mz[p] = 0u; }
        __syncthreads();

        // ================= forward both nets =================
        for (int net = 0; net < 2; ++net) {
            const unsigned short* w1t = ws + OW1T(net);
            const unsigned short* w2t = ws + OW2T(net);
            const float* b1p = net ? b1b : b1a;
            const float* b2p = net ? b2b : b2a;
            const float* w3p = net ? w3bf : w3af;

            // ---- L1 ----
            f4 acc[2][4];
            #pragma unroll
            for (int h = 0; h < 2; ++h)
                #pragma unroll
                for (int s = 0; s < 4; ++s) acc[h][s] = (f4){0.f,0.f,0.f,0.f};
            #pragma unroll
            for (int k0 = 0; k0 < 96; k0 += 32) {
                bf8 a0 = *(const bf8*)&A0s[ mp     *96 + k0 + q*8];
                bf8 a1 = *(const bf8*)&A0s[(16+mp) *96 + k0 + q*8];
                #pragma unroll
                for (int s = 0; s < 4; ++s) {
                    bf8 bb = *(const bf8*)(w1t + (size_t)(nb + s*16 + mp)*96 + k0 + q*8);
                    acc[0][s] = MFMA(a0, bb, acc[0][s]);
                    acc[1][s] = MFMA(a1, bb, acc[1][s]);
                }
            }
            #pragma unroll
            for (int h = 0; h < 2; ++h) {
                int m0 = h*16;
                #pragma unroll
                for (int s = 0; s < 4; ++s) {
                    int n0 = nb + s*16, col = n0 + mp;
                    float bias = b1p[col];
                    #pragma unroll
                    for (int r = 0; r < 4; ++r) {
                        float v = acc[h][s][r] + bias;
                        bool pos = v > 0.f;
                        unsigned long long bal = __ballot(pos);
                        h1s[(m0 + q*4 + r)*264 + col] = f2bf(pos ? v : 0.f);
                        if (mp == 0)
                            atomicOr(&maskS[net][0][m0 + q*4 + r][n0 >> 5],
                                     ((unsigned)((bal >> (q*16)) & 0xFFFFull)) << (n0 & 16));
                    }
                }
            }
            __syncthreads();

            // ---- L2 ----
            #pragma unroll
            for (int h = 0; h < 2; ++h)
                #pragma unroll
                for (int s = 0; s < 4; ++s) acc[h][s] = (f4){0.f,0.f,0.f,0.f};
            for (int k0 = 0; k0 < 256; k0 += 32) {
                bf8 a0 = *(const bf8*)&h1s[ mp     *264 + k0 + q*8];
                bf8 a1 = *(const bf8*)&h1s[(16+mp) *264 + k0 + q*8];
                #pragma unroll
                for (int s = 0; s < 4; ++s) {
                    bf8 bb = *(const bf8*)(w2t + (size_t)(nb + s*16 + mp)*256 + k0 + q*8);
                    acc[0][s] = MFMA(a0, bb, acc[0][s]);
                    acc[1][s] = MFMA(a1, bb, acc[1][s]);
                }
            }
            float qp[2][4] = {{0.f,0.f,0.f,0.f},{0.f,0.f,0.f,0.f}};
            #pragma unroll
            for (int h = 0; h < 2; ++h) {
                int m0 = h*16;
                #pragma unroll
                for (int s = 0; s < 4; ++s) {
                    int n0 = nb + s*16, col = n0 + mp;
                    float bias = b2p[col], w3v = w3p[col];
                    #pragma unroll
                    for (int r = 0; r < 4; ++r) {
                        float v = acc[h][s][r] + bias;
                        bool pos = v > 0.f;
                        unsigned long long bal = __ballot(pos);
                        if (mp == 0)
                            atomicOr(&maskS[net][1][m0 + q*4 + r][n0 >> 5],
                                     ((unsigned)((bal >> (q*16)) & 0xFFFFull)) << (n0 & 16));
                        qp[h][r] += pos ? v * w3v : 0.f;
                    }
                }
            }
            #pragma unroll
            for (int d = 1; d < 16; d <<= 1)
                #pragma unroll
                for (int h = 0; h < 2; ++h)
                    #pragma unroll
                    for (int r = 0; r < 4; ++r)
                        qp[h][r] += __shfl_xor(qp[h][r], d, 64);
            if (mp == 0) {
                #pragma unroll
                for (int h = 0; h < 2; ++h)
                    #pragma unroll
                    for (int r = 0; r < 4; ++r)
                        qpart[net][wv][h*16 + q*4 + r] = qp[h][r];
            }
            __syncthreads();
        }

        // ======= argmin =======
        if (t < 32) {
            float q0 = qpart[0][0][t] + qpart[0][1][t] + qpart[0][2][t] + qpart[0][3][t] + b3a[0];
            float q1 = qpart[1][0][t] + qpart[1][1][t] + qpart[1][2][t] + qpart[1][3][t] + b3b[0];
            winsS[t] = (q0 <= q1) ? 0 : 1;
        }
        __syncthreads();

        // ============ backward both nets + score ============
        for (int net = 0; net < 2; ++net) {
            const unsigned short* w2c = ws + OW2C(net);
            const unsigned short* w3b8 = ws + OW3B(net);

            f4 acc[2][4];
            #pragma unroll
            for (int h = 0; h < 2; ++h)
                #pragma unroll
                for (int s = 0; s < 4; ++s) acc[h][s] = (f4){0.f,0.f,0.f,0.f};
            const int win0 = (winsS[mp] == net), win1 = (winsS[16+mp] == net);
            for (int k0 = 0; k0 < 256; k0 += 32) {
                bf8 w3v = *(const bf8*)(w3b8 + k0 + q*8);
                unsigned bits0 = win0 ? ((maskS[net][1][mp]   [k0 >> 5] >> (q*8)) & 0xFFu) : 0u;
                unsigned bits1 = win1 ? ((maskS[net][1][16+mp][k0 >> 5] >> (q*8)) & 0xFFu) : 0u;
                bf8 a0, a1;
                #pragma unroll
                for (int j = 0; j < 8; ++j) {
                    a0[j] = ((bits0 >> j) & 1u) ? w3v[j] : (short)0;
                    a1[j] = ((bits1 >> j) & 1u) ? w3v[j] : (short)0;
                }
                #pragma unroll
                for (int s = 0; s < 4; ++s) {
                    bf8 bb = *(const bf8*)(w2c + (size_t)(nb + s*16 + mp)*256 + k0 + q*8);
                    acc[0][s] = MFMA(a0, bb, acc[0][s]);
                    acc[1][s] = MFMA(a1, bb, acc[1][s]);
                }
            }
            #pragma unroll
            for (int h = 0; h < 2; ++h) {
                int m0 = h*16;
                #pragma unroll
                for (int s = 0; s < 4; ++s) {
                    int col = nb + s*16 + mp;
                    #pragma unroll
                    for (int r = 0; r < 4; ++r) {
                        int row = m0 + q*4 + r;
                        bool on = (maskS[net][0][row][col >> 5] >> (col & 31)) & 1u;
                        g1s[row*264 + col] = f2bf(on ? acc[h][s][r] : 0.f);
                    }
                }
            }
            __syncthreads();
            // score tile per wave: rows (wv&1)*16.., cols (wv>>1)*16..
            {
                int m0 = (wv & 1)*16, d0 = (wv >> 1)*16;
                const unsigned short* w1x = ws + OW1X(net);
                f4 sa = (f4){0.f,0.f,0.f,0.f};
                for (int k0 = 0; k0 < 256; k0 += 32) {
                    bf8 aa = *(const bf8*)&g1s[(m0 + mp)*264 + k0 + q*8];
                    bf8 bb = *(const bf8*)(w1x + (size_t)(d0 + mp)*256 + k0 + q*8);
                    sa = MFMA(aa, bb, sa);
                }
                int colD = d0 + mp;
                if (colD < 20) {
                    #pragma unroll
                    for (int r = 0; r < 4; ++r) {
                        int row = m0 + q*4 + r;
                        if (net == 0) scoreS[row*21 + colD]  = sa[r];
                        else          scoreS[row*21 + colD] += sa[r];
                    }
                }
            }
            __syncthreads();
        }

        // ================= RBF / median / phi / logp =================
        for (int p = t; p < 1024; p += 256) {
            int i = p >> 5, j = p & 31;
            float s = 0.f;
            #pragma unroll
            for (int d = 0; d < 20; ++d) {
                float df = Xm[i*20 + d] - Xm[j*20 + d];
                s += df * df;
            }
            d2s[p] = s;
        }
        __syncthreads();
        if (wv == 0) {
            // in-register bitonic sort of the 496 pair values (+16 inf), 8/lane, no barriers
            float v[8];
            #pragma unroll
            for (int i = 0; i < 8; ++i) {
                int e = lane*8 + i;
                v[i] = (e < 496) ? d2s[lutI[e]*32 + lutJ[e]] : 3.4e38f;
            }
            for (int k = 2; k <= 512; k <<= 1) {
                for (int jj = k >> 1; jj >= 8; jj >>= 1) {
                    int lm = jj >> 3;
                    #pragma unroll
                    for (int i = 0; i < 8; ++i) {
                        float w = __shfl_xor(v[i], lm, 64);
                        int p = lane*8 + i;
                        bool takeMin = (((p & k) == 0) == ((p & jj) == 0));
                        v[i] = takeMin ? fminf(v[i], w) : fmaxf(v[i], w);
                    }
                }
                int jj0 = (k >> 1) < 4 ? (k >> 1) : 4;
                for (int jj = jj0; jj >= 1; jj >>= 1) {
                    #pragma unroll
                    for (int i = 0; i < 8; ++i) {
                        if ((i & jj) == 0) {
                            int i2 = i | jj;
                            int p = lane*8 + i;
                            bool up = ((p & k) == 0);
                            float x = v[i], y = v[i2];
                            float mn = fminf(x, y), mx = fmaxf(x, y);
                            v[i] = up ? mn : mx; v[i2] = up ? mx : mn;
                        }
                    }
                }
            }
            if (lane == 29) med2[0] = v[7];   // sorted index 239
            if (lane == 30) med2[1] = v[0];   // sorted index 240
        } else {
            for (int p = t - 64; p < 1024; p += 192) {
                int i = p >> 5, j = p & 31;
                float s = 0.f;
                #pragma unroll
                for (int d = 0; d < 20; ++d)
                    s += (Xm[i*20 + d] - Xm[j*20 + d]) * scoreS[j*21 + d];
                dots[p] = s;
            }
        }
        __syncthreads();
        float med   = 0.5f * (med2[0] + med2[1]);
        float gamma = 1.f / (2.f * (med / (2.f * logf(33.f))) + 1e-8f);
        for (int p = t; p < 1024; p += 256) {
            int i = p >> 5, j = p & 31;
            float Kij = expf(-gamma * d2s[p]);
            Kms[p] = Kij;
            float c1  = -2.f * gamma * Kij * dots[p];
            float inn = 2.f * gamma * Kij * d2s[p] - 20.f * (Kij - (i == j ? 1.f : 0.f));
            Spair[i*33 + j] = c1 - 2.f * gamma * inn;
        }
        __syncthreads();
        {
            int i = t & 31, dg = t >> 5;
            for (int dd = dg; dd < 20; dd += 8) {
                float xi = Xm[i*20 + dd];
                float s = 0.f;
                for (int j = 0; j < 32; ++j) {
                    float Kij = Kms[i*32 + j];
                    s += Kij * (scoreS[j*21 + dd] + 2.f * gamma * (xi - Xm[j*20 + dd]));
                }
                phis[i*20 + dd] = s * (1.f/32.f);
            }
        }
        if (t < 32) {
            float s = 0.f;
            #pragma unroll
            for (int j = 0; j < 32; ++j) s += Spair[t*33 + j];
            logps[t] -= LRC * (s * (1.f/32.f));
        }
        __syncthreads();
        for (int p = t; p < 640; p += 256) {
            int i = p / 20, d = p - i*20;
            float nx = Xm[p] + LRC * phis[p];
            Xm[p] = nx;
            A0s[i*96 + 64 + d] = f2bf(nx);
        }
        __syncthreads();
    } // steps

    // ================= epilogue =================
    for (int p = t; p < 640; p += 256) {
        int i = p / 20, d = p - i*20;
        out[(b*32 + i)*20 + d] = tanhf(Xm[p]);
    }
    if (t < 32) {
        float lt = 0.f, s0 = 0.f;
        for (int d = 0; d < 20; ++d) {
            float a  = Xm[t*20 + d];
            float x  = -2.f * a;
            float sp = fmaxf(x, 0.f) + log1pf(expf(-fabsf(x)));
            lt -= 2.f * (0.69314718056f - a - sp);
            float v = a0g[(b*32 + t)*20 + d];
            s0 += v * v;
        }
        qvS[t] = -18.3787706641f - 0.5f*s0 + logps[t] + lt;
    }
    __syncthreads();
    if (t == 0) {
        float s = 0.f;
        for (int i = 0; i < 32; ++i) s += qvS[i];
        out[1024*32*20 + b] = s * (1.f/32.f);
    }
}

extern "C" void kernel_launch(void* const* d_in, const int* in_sizes, int n_in,
                              void* d_out, int out_size, void* d_ws, size_t ws_size,
                              hipStream_t stream) {
    unsigned short* ws = (unsigned short*)d_ws;
    prep_weights<<<(WS_ELEMS + 255)/256, 256, 0, stream>>>(
        (const float*)d_in[2],  (const float*)d_in[4],  (const float*)d_in[6],
        (const float*)d_in[8],  (const float*)d_in[10], (const float*)d_in[12], ws);
    svgd_main<<<1024, 256, 0, stream>>>(
        (const float*)d_in[0],  (const float*)d_in[1],
        (const float*)d_in[3],  (const float*)d_in[5],  (const float*)d_in[7],
        (const float*)d_in[9],  (const float*)d_in[11], (const float*)d_in[13],
        (const float*)d_in[6],  (const float*)d_in[12],
        ws, (float*)d_out);
}

// Round 3
// 500.066 us; speedup vs baseline: 4.7281x; 1.7694x over previous
//
#include <hip/hip_runtime.h>
#include <math.h>

#define NPART 32
#define ADIM  20
#define ODIM  64
#define HID   256
#define NSTEPS 5
#define LRC   0.1f
#define NBLK  512     // 2 states per block

typedef short bf8 __attribute__((ext_vector_type(8)));   // 8 bf16 (4 VGPRs)
typedef float f4  __attribute__((ext_vector_type(4)));   // MFMA C/D

// workspace layout (bf16 element offsets)
#define OW1T(n) ((n)*24576)             // [256 n][96 k]   w1^T, k-pad 84->96 (fwd L1 B)
#define OW2T(n) (49152 + (n)*65536)     // [256 n][256 k]  w2^T (fwd L2 B)
#define OW2C(n) (180224 + (n)*65536)    // raw w2 copy (bwd dh1 B)
#define OW1X(n) (311296 + (n)*8192)     // [32 d][256 n]   w1 act-rows (score B)
#define OW3B(n) (327680 + (n)*256)      // w3 bf16
#define WS_ELEMS 328192

__device__ __forceinline__ short f2bf(float x) {          // RNE f32->bf16
    unsigned u = __float_as_uint(x);
    u += 0x7FFFu + ((u >> 16) & 1u);
    return (short)(u >> 16);
}

#define MFMA(a,b,c) __builtin_amdgcn_mfma_f32_16x16x32_bf16((a),(b),(c),0,0,0)

// ---------- prep: build bf16 weight images in ws ----------
__global__ void prep_weights(const float* __restrict__ w1a, const float* __restrict__ w2a,
                             const float* __restrict__ w3a, const float* __restrict__ w1b,
                             const float* __restrict__ w2b, const float* __restrict__ w3b,
                             unsigned short* __restrict__ ws)
{
    int idx = blockIdx.x * 256 + threadIdx.x;
    if (idx >= WS_ELEMS) return;
    float val;
    if (idx < 49152) {
        int net = idx / 24576, rem = idx % 24576;
        int n = rem / 96, k = rem % 96;
        const float* w1 = net ? w1b : w1a;
        val = (k < 84) ? w1[k*256 + n] : 0.f;
    } else if (idx < 180224) {
        int t2 = idx - 49152; int net = t2 / 65536, rem = t2 % 65536;
        int n = rem / 256, k = rem % 256;
        const float* w2 = net ? w2b : w2a;
        val = w2[k*256 + n];
    } else if (idx < 311296) {
        int t2 = idx - 180224; int net = t2 / 65536, rem = t2 % 65536;
        const float* w2 = net ? w2b : w2a;
        val = w2[rem];
    } else if (idx < 327680) {
        int t2 = idx - 311296; int net = t2 / 8192, rem = t2 % 8192;
        int d = rem / 256, n = rem % 256;
        const float* w1 = net ? w1b : w1a;
        val = (d < 20) ? w1[(64 + d)*256 + n] : 0.f;
    } else {
        int t2 = idx - 327680; int net = t2 / 256, k = t2 % 256;
        const float* w3 = net ? w3b : w3a;
        val = w3[k];
    }
    ws[idx] = (unsigned short)f2bf(val);
}

// ---------- main: 2 states per block, 512 threads ----------
__global__ void __launch_bounds__(512, 4)
svgd_main(const float* __restrict__ obs,  const float* __restrict__ a0g,
          const float* __restrict__ b1a,  const float* __restrict__ b2a, const float* __restrict__ b3a,
          const float* __restrict__ b1b,  const float* __restrict__ b2b, const float* __restrict__ b3b,
          const float* __restrict__ w3af, const float* __restrict__ w3bf,
          const unsigned short* __restrict__ ws, float* __restrict__ out)
{
    __shared__ __align__(16) short A0s[64*96];      // [obs|X|pad] bf16, 2 states stacked
    __shared__ __align__(16) short hbuf[64*264];    // h1 / g1 bf16; RBF fp32 arrays alias
    __shared__ unsigned maskS[2][2][64][8];         // relu bitmasks
    __shared__ float Xm[64*20];                     // fp32 master particles
    __shared__ float scoreS[64*21];
    __shared__ float phis[64*20];
    __shared__ float qpart[2][8][64];
    __shared__ int   winsS[64];
    __shared__ float logps[64];
    __shared__ unsigned short lutI[496], lutJ[496];
    __shared__ float med2[4];                        // [state][2]
    __shared__ float qvS[64];

    const int t = threadIdx.x, b = blockIdx.x;
    const int lane = t & 63, wv = t >> 6;           // 8 waves
    const int q = lane >> 4, mp = lane & 15;
    const int nb = wv * 32;                          // 32-col slice of the 256-wide GEMMs

    // ---- init ----
    for (int p = t; p < 64*ODIM; p += 512) {
        int i = p >> 6, d = p & 63;
        A0s[i*96 + d] = f2bf(obs[(b*64 + i)*ODIM + d]);
    }
    for (int p = t; p < 64*ADIM; p += 512) {
        int i = p / 20, d = p - i*20;
        float v = a0g[(b*64 + i)*20 + d];
        Xm[p] = v;
        A0s[i*96 + 64 + d] = f2bf(v);
    }
    for (int p = t; p < 64*12; p += 512) { int i = p/12, d = p - i*12; A0s[i*96 + 84 + d] = 0; }
    if (t < 496) {
        int i_ = 0, rem = t;
        while (rem >= 31 - i_) { rem -= 31 - i_; ++i_; }
        lutI[t] = (unsigned short)i_; lutJ[t] = (unsigned short)(i_ + 1 + rem);
    }
    if (t < 64) logps[t] = 0.f;
    __syncthreads();

    for (int step = 0; step < NSTEPS; ++step) {
        { unsigned* mz = &maskS[0][0][0][0];
          for (int p = t; p < 2*2*64*8; p += 512) mz[p] = 0u; }
        __syncthreads();

        // ================= forward both nets =================
        for (int net = 0; net < 2; ++net) {
            const unsigned short* w1t = ws + OW1T(net);
            const unsigned short* w2t = ws + OW2T(net);
            const float* b1p = net ? b1b : b1a;
            const float* b2p = net ? b2b : b2a;
            const float* w3p = net ? w3bf : w3af;

            // ---- L1: [64 x 96] @ w1t -> h1 ----
            f4 acc[4][2];
            #pragma unroll
            for (int h = 0; h < 4; ++h) { acc[h][0] = (f4){0,0,0,0}; acc[h][1] = (f4){0,0,0,0}; }
            {
                const unsigned short* bp0 = w1t + (size_t)(nb +      mp)*96 + q*8;
                const unsigned short* bp1 = w1t + (size_t)(nb + 16 + mp)*96 + q*8;
                bf8 bb0 = *(const bf8*)bp0, bb1 = *(const bf8*)bp1;
                #pragma unroll
                for (int k0 = 0; k0 < 96; k0 += 32) {
                    bf8 n0 = bb0, n1 = bb1;
                    if (k0 + 32 < 96) { n0 = *(const bf8*)(bp0 + k0 + 32); n1 = *(const bf8*)(bp1 + k0 + 32); }
                    #pragma unroll
                    for (int h = 0; h < 4; ++h) {
                        bf8 aa = *(const bf8*)&A0s[(h*16 + mp)*96 + k0 + q*8];
                        acc[h][0] = MFMA(aa, bb0, acc[h][0]);
                        acc[h][1] = MFMA(aa, bb1, acc[h][1]);
                    }
                    bb0 = n0; bb1 = n1;
                }
            }
            #pragma unroll
            for (int h = 0; h < 4; ++h) {
                #pragma unroll
                for (int s = 0; s < 2; ++s) {
                    int n0 = nb + s*16, col = n0 + mp;
                    float bias = b1p[col];
                    #pragma unroll
                    for (int r = 0; r < 4; ++r) {
                        float v = acc[h][s][r] + bias;
                        bool pos = v > 0.f;
                        unsigned long long bal = __ballot(pos);
                        hbuf[(h*16 + q*4 + r)*264 + col] = f2bf(pos ? v : 0.f);
                        if (mp == 0)
                            atomicOr(&maskS[net][0][h*16 + q*4 + r][n0 >> 5],
                                     ((unsigned)((bal >> (q*16)) & 0xFFFFull)) << (n0 & 16));
                    }
                }
            }
            __syncthreads();

            // ---- L2: h1 @ w2t ----
            #pragma unroll
            for (int h = 0; h < 4; ++h) { acc[h][0] = (f4){0,0,0,0}; acc[h][1] = (f4){0,0,0,0}; }
            {
                const unsigned short* bp0 = w2t + (size_t)(nb +      mp)*256 + q*8;
                const unsigned short* bp1 = w2t + (size_t)(nb + 16 + mp)*256 + q*8;
                bf8 bb0 = *(const bf8*)bp0, bb1 = *(const bf8*)bp1;
                #pragma unroll
                for (int k0 = 0; k0 < 256; k0 += 32) {
                    bf8 n0 = bb0, n1 = bb1;
                    if (k0 + 32 < 256) { n0 = *(const bf8*)(bp0 + k0 + 32); n1 = *(const bf8*)(bp1 + k0 + 32); }
                    #pragma unroll
                    for (int h = 0; h < 4; ++h) {
                        bf8 aa = *(const bf8*)&hbuf[(h*16 + mp)*264 + k0 + q*8];
                        acc[h][0] = MFMA(aa, bb0, acc[h][0]);
                        acc[h][1] = MFMA(aa, bb1, acc[h][1]);
                    }
                    bb0 = n0; bb1 = n1;
                }
            }
            {
                float qp[4][4] = {{0,0,0,0},{0,0,0,0},{0,0,0,0},{0,0,0,0}};
                #pragma unroll
                for (int h = 0; h < 4; ++h) {
                    #pragma unroll
                    for (int s = 0; s < 2; ++s) {
                        int n0 = nb + s*16, col = n0 + mp;
                        float bias = b2p[col], w3v = w3p[col];
                        #pragma unroll
                        for (int r = 0; r < 4; ++r) {
                            float v = acc[h][s][r] + bias;
                            bool pos = v > 0.f;
                            unsigned long long bal = __ballot(pos);
                            if (mp == 0)
                                atomicOr(&maskS[net][1][h*16 + q*4 + r][n0 >> 5],
                                         ((unsigned)((bal >> (q*16)) & 0xFFFFull)) << (n0 & 16));
                            qp[h][r] += pos ? v * w3v : 0.f;
                        }
                    }
                }
                #pragma unroll
                for (int d = 1; d < 16; d <<= 1)
                    #pragma unroll
                    for (int h = 0; h < 4; ++h)
                        #pragma unroll
                        for (int r = 0; r < 4; ++r)
                            qp[h][r] += __shfl_xor(qp[h][r], d, 64);
                if (mp == 0) {
                    #pragma unroll
                    for (int h = 0; h < 4; ++h)
                        #pragma unroll
                        for (int r = 0; r < 4; ++r)
                            qpart[net][wv][h*16 + q*4 + r] = qp[h][r];
                }
            }
            __syncthreads();
        }

        // ======= argmin =======
        if (t < 64) {
            float q0 = b3a[0], q1 = b3b[0];
            #pragma unroll
            for (int w = 0; w < 8; ++w) { q0 += qpart[0][w][t]; q1 += qpart[1][w][t]; }
            winsS[t] = (q0 <= q1) ? 0 : 1;
        }
        __syncthreads();

        // ============ backward both nets + score ============
        for (int net = 0; net < 2; ++net) {
            const unsigned short* w2c  = ws + OW2C(net);
            const unsigned short* w3b8 = ws + OW3B(net);

            f4 acc[4][2];
            #pragma unroll
            for (int h = 0; h < 4; ++h) { acc[h][0] = (f4){0,0,0,0}; acc[h][1] = (f4){0,0,0,0}; }
            int win[4];
            #pragma unroll
            for (int h = 0; h < 4; ++h) win[h] = (winsS[h*16 + mp] == net);
            {
                const unsigned short* bp0 = w2c + (size_t)(nb +      mp)*256 + q*8;
                const unsigned short* bp1 = w2c + (size_t)(nb + 16 + mp)*256 + q*8;
                bf8 bb0 = *(const bf8*)bp0, bb1 = *(const bf8*)bp1;
                #pragma unroll
                for (int k0 = 0; k0 < 256; k0 += 32) {
                    bf8 n0 = bb0, n1 = bb1;
                    if (k0 + 32 < 256) { n0 = *(const bf8*)(bp0 + k0 + 32); n1 = *(const bf8*)(bp1 + k0 + 32); }
                    bf8 w3v = *(const bf8*)(w3b8 + k0 + q*8);
                    #pragma unroll
                    for (int h = 0; h < 4; ++h) {
                        unsigned bits = win[h] ? ((maskS[net][1][h*16 + mp][k0 >> 5] >> (q*8)) & 0xFFu) : 0u;
                        bf8 aa;
                        #pragma unroll
                        for (int j = 0; j < 8; ++j)
                            aa[j] = ((bits >> j) & 1u) ? w3v[j] : (short)0;
                        acc[h][0] = MFMA(aa, bb0, acc[h][0]);
                        acc[h][1] = MFMA(aa, bb1, acc[h][1]);
                    }
                    bb0 = n0; bb1 = n1;
                }
            }
            #pragma unroll
            for (int h = 0; h < 4; ++h) {
                #pragma unroll
                for (int s = 0; s < 2; ++s) {
                    int col = nb + s*16 + mp;
                    #pragma unroll
                    for (int r = 0; r < 4; ++r) {
                        int row = h*16 + q*4 + r;
                        bool on = (maskS[net][0][row][col >> 5] >> (col & 31)) & 1u;
                        hbuf[row*264 + col] = f2bf(on ? acc[h][s][r] : 0.f);
                    }
                }
            }
            __syncthreads();
            // score: wave -> (m-tile, col-half)
            {
                int mt = wv & 3, ch = wv >> 2;
                const unsigned short* w1x = ws + OW1X(net);
                const unsigned short* bp  = w1x + (size_t)(ch*16 + mp)*256 + q*8;
                f4 sa = (f4){0,0,0,0};
                bf8 bx = *(const bf8*)bp;
                #pragma unroll
                for (int k0 = 0; k0 < 256; k0 += 32) {
                    bf8 nx = bx;
                    if (k0 + 32 < 256) nx = *(const bf8*)(bp + k0 + 32);
                    bf8 aa = *(const bf8*)&hbuf[(mt*16 + mp)*264 + k0 + q*8];
                    sa = MFMA(aa, bx, sa);
                    bx = nx;
                }
                int colD = ch*16 + mp;
                if (colD < 20) {
                    #pragma unroll
                    for (int r = 0; r < 4; ++r) {
                        int row = mt*16 + q*4 + r;
                        if (net == 0) scoreS[row*21 + colD]  = sa[r];
                        else          scoreS[row*21 + colD] += sa[r];
                    }
                }
            }
            __syncthreads();
        }

        // ================= RBF / median / phi / logp =================
        float* d2s   = (float*)hbuf;        // [2][1024]
        float* dots  = d2s + 2048;
        float* Kms   = dots + 2048;
        float* Spair = Kms + 2048;          // [2][32][33]
        for (int p = t; p < 2048; p += 512) {
            int st = p >> 10, i = (p >> 5) & 31, j = p & 31;
            float s = 0.f;
            #pragma unroll
            for (int d = 0; d < 20; ++d) {
                float df = Xm[(st*32 + i)*20 + d] - Xm[(st*32 + j)*20 + d];
                s += df * df;
            }
            d2s[p] = s;
        }
        __syncthreads();
        if (wv < 2) {
            const float* base = d2s + wv*1024;
            float v[8];
            #pragma unroll
            for (int i = 0; i < 8; ++i) {
                int e = lane*8 + i;
                v[i] = (e < 496) ? base[lutI[e]*32 + lutJ[e]] : 3.4e38f;
            }
            for (int k = 2; k <= 512; k <<= 1) {
                for (int jj = k >> 1; jj >= 8; jj >>= 1) {
                    int lm = jj >> 3;
                    #pragma unroll
                    for (int i = 0; i < 8; ++i) {
                        float w = __shfl_xor(v[i], lm, 64);
                        int p = lane*8 + i;
                        bool takeMin = (((p & k) == 0) == ((p & jj) == 0));
                        v[i] = takeMin ? fminf(v[i], w) : fmaxf(v[i], w);
                    }
                }
                int jj0 = (k >> 1) < 4 ? (k >> 1) : 4;
                for (int jj = jj0; jj >= 1; jj >>= 1) {
                    #pragma unroll
                    for (int i = 0; i < 8; ++i) {
                        if ((i & jj) == 0) {
                            int i2 = i | jj;
                            int p = lane*8 + i;
                            bool up = ((p & k) == 0);
                            float x = v[i], y = v[i2];
                            float mn = fminf(x, y), mx = fmaxf(x, y);
                            v[i] = up ? mn : mx; v[i2] = up ? mx : mn;
                        }
                    }
                }
            }
            if (lane == 29) med2[wv*2 + 0] = v[7];   // sorted index 239
            if (lane == 30) med2[wv*2 + 1] = v[0];   // sorted index 240
        } else {
            for (int p = t - 128; p < 2048; p += 384) {
                int st = p >> 10, i = (p >> 5) & 31, j = p & 31;
                float s = 0.f;
                #pragma unroll
                for (int d = 0; d < 20; ++d)
                    s += (Xm[(st*32 + i)*20 + d] - Xm[(st*32 + j)*20 + d])
                         * scoreS[(st*32 + j)*21 + d];
                dots[p] = s;
            }
        }
        __syncthreads();
        for (int p = t; p < 2048; p += 512) {
            int st = p >> 10, i = (p >> 5) & 31, j = p & 31;
            float med   = 0.5f * (med2[st*2] + med2[st*2 + 1]);
            float gamma = 1.f / (2.f * (med / (2.f * logf(33.f))) + 1e-8f);
            float Kij = expf(-gamma * d2s[p]);
            Kms[p] = Kij;
            float c1  = -2.f * gamma * Kij * dots[p];
            float inn = 2.f * gamma * Kij * d2s[p] - 20.f * (Kij - (i == j ? 1.f : 0.f));
            Spair[st*1056 + i*33 + j] = c1 - 2.f * gamma * inn;
        }
        __syncthreads();
        {
            int i = t & 63, dg = t >> 6;
            int st = i >> 5, il = i & 31;
            float med   = 0.5f * (med2[st*2] + med2[st*2 + 1]);
            float gamma = 1.f / (2.f * (med / (2.f * logf(33.f))) + 1e-8f);
            for (int dd = dg; dd < 20; dd += 8) {
                float xi = Xm[i*20 + dd];
                float s = 0.f;
                for (int j = 0; j < 32; ++j) {
                    float Kij = Kms[st*1024 + il*32 + j];
                    s += Kij * (scoreS[(st*32 + j)*21 + dd]
                                + 2.f * gamma * (xi - Xm[(st*32 + j)*20 + dd]));
                }
                phis[i*20 + dd] = s * (1.f/32.f);
            }
        }
        if (t < 64) {
            int st = t >> 5;
            float s = 0.f;
            #pragma unroll
            for (int j = 0; j < 32; ++j) s += Spair[st*1056 + (t & 31)*33 + j];
            logps[t] -= LRC * (s * (1.f/32.f));
        }
        __syncthreads();
        for (int p = t; p < 64*20; p += 512) {
            int i = p / 20, d = p - i*20;
            float nx = Xm[p] + LRC * phis[p];
            Xm[p] = nx;
            A0s[i*96 + 64 + d] = f2bf(nx);
        }
        __syncthreads();
    } // steps

    // ================= epilogue =================
    for (int p = t; p < 64*20; p += 512) {
        int i = p / 20, d = p - i*20;
        out[(b*64 + i)*20 + d] = tanhf(Xm[p]);
    }
    if (t < 64) {
        float lt = 0.f, s0 = 0.f;
        for (int d = 0; d < 20; ++d) {
            float a  = Xm[t*20 + d];
            float x  = -2.f * a;
            float sp = fmaxf(x, 0.f) + log1pf(expf(-fabsf(x)));
            lt -= 2.f * (0.69314718056f - a - sp);
            float v = a0g[(b*64 + t)*20 + d];
            s0 += v * v;
        }
        qvS[t] = -18.3787706641f - 0.5f*s0 + logps[t] + lt;
    }
    __syncthreads();
    if (t < 2) {
        float s = 0.f;
        for (int i = 0; i < 32; ++i) s += qvS[t*32 + i];
        out[1024*32*20 + b*2 + t] = s * (1.f/32.f);
    }
}

extern "C" void kernel_launch(void* const* d_in, const int* in_sizes, int n_in,
                              void* d_out, int out_size, void* d_ws, size_t ws_size,
                              hipStream_t stream) {
    unsigned short* ws = (unsigned short*)d_ws;
    prep_weights<<<(WS_ELEMS + 255)/256, 256, 0, stream>>>(
        (const float*)d_in[2],  (const float*)d_in[4],  (const float*)d_in[6],
        (const float*)d_in[8],  (const float*)d_in[10], (const float*)d_in[12], ws);
    svgd_main<<<NBLK, 512, 0, stream>>>(
        (const float*)d_in[0],  (const float*)d_in[1],
        (const float*)d_in[3],  (const float*)d_in[5],  (const float*)d_in[7],
        (const float*)d_in[9],  (const float*)d_in[11], (const float*)d_in[13],
        (const float*)d_in[6],  (const float*)d_in[12],
        ws, (float*)d_out);
}

// Round 4
// 497.517 us; speedup vs baseline: 4.7523x; 1.0051x over previous
//
#include <hip/hip_runtime.h>
#include <math.h>

#define NPART 32
#define ADIM  20
#define ODIM  64
#define HID   256
#define NSTEPS 5
#define LRC   0.1f
#define NBLK  512     // 2 states per block
#define LOG33 3.4965075614664802f

typedef short bf8 __attribute__((ext_vector_type(8)));   // 8 bf16 (4 VGPRs)
typedef float f4  __attribute__((ext_vector_type(4)));   // MFMA C/D

// workspace layout (bf16 element offsets)
#define OW1T(n) ((n)*24576)             // [256 n][96 k]   w1^T, k-pad 84->96 (fwd L1 B)
#define OW2T(n) (49152 + (n)*65536)     // [256 n][256 k]  w2^T (fwd L2 B)
#define OW2C(n) (180224 + (n)*65536)    // raw w2 copy (bwd dh1 B)
#define OW1X(n) (311296 + (n)*8192)     // [32 d][256 n]   w1 act-rows (score B)
#define OW3B(n) (327680 + (n)*256)      // w3 bf16
#define WS_ELEMS 328192

__device__ __forceinline__ short f2bf(float x) {          // RNE f32->bf16 (prep only)
    unsigned u = __float_as_uint(x);
    u += 0x7FFFu + ((u >> 16) & 1u);
    return (short)(u >> 16);
}
__device__ __forceinline__ short f2bfT(float x) {         // truncating f32->bf16 (fast)
    return (short)(__float_as_uint(x) >> 16);
}
__device__ __forceinline__ float bf2f(short s) {
    return __uint_as_float(((unsigned)(unsigned short)s) << 16);
}

#define MFMA(a,b,c) __builtin_amdgcn_mfma_f32_16x16x32_bf16((a),(b),(c),0,0,0)

// ---------- prep: build bf16 weight images in ws ----------
__global__ void prep_weights(const float* __restrict__ w1a, const float* __restrict__ w2a,
                             const float* __restrict__ w3a, const float* __restrict__ w1b,
                             const float* __restrict__ w2b, const float* __restrict__ w3b,
                             unsigned short* __restrict__ ws)
{
    int idx = blockIdx.x * 256 + threadIdx.x;
    if (idx >= WS_ELEMS) return;
    float val;
    if (idx < 49152) {
        int net = idx / 24576, rem = idx % 24576;
        int n = rem / 96, k = rem % 96;
        const float* w1 = net ? w1b : w1a;
        val = (k < 84) ? w1[k*256 + n] : 0.f;
    } else if (idx < 180224) {
        int t2 = idx - 49152; int net = t2 / 65536, rem = t2 % 65536;
        int n = rem / 256, k = rem % 256;
        const float* w2 = net ? w2b : w2a;
        val = w2[k*256 + n];
    } else if (idx < 311296) {
        int t2 = idx - 180224; int net = t2 / 65536, rem = t2 % 65536;
        const float* w2 = net ? w2b : w2a;
        val = w2[rem];
    } else if (idx < 327680) {
        int t2 = idx - 311296; int net = t2 / 8192, rem = t2 % 8192;
        int d = rem / 256, n = rem % 256;
        const float* w1 = net ? w1b : w1a;
        val = (d < 20) ? w1[(64 + d)*256 + n] : 0.f;
    } else {
        int t2 = idx - 327680; int net = t2 / 256, k = t2 % 256;
        const float* w3 = net ? w3b : w3a;
        val = w3[k];
    }
    ws[idx] = (unsigned short)f2bf(val);
}

// ---------- main: 2 states per block, 512 threads ----------
__global__ void __launch_bounds__(512, 4)
svgd_main(const float* __restrict__ obs,  const float* __restrict__ a0g,
          const float* __restrict__ b1a,  const float* __restrict__ b2a, const float* __restrict__ b3a,
          const float* __restrict__ b1b,  const float* __restrict__ b2b, const float* __restrict__ b3b,
          const float* __restrict__ w3af, const float* __restrict__ w3bf,
          const unsigned short* __restrict__ ws, float* __restrict__ out)
{
    __shared__ __align__(16) short A0s[64*96];      // [obs|X|pad] bf16, 2 states stacked
    __shared__ __align__(16) short hbuf[64*264];    // h1/g1 bf16; RBF shadows alias (see below)
    __shared__ unsigned maskS[2][2][64][8];         // relu bitmasks
    __shared__ float Xm[64*20];                     // fp32 master particles
    __shared__ float scoreS[64*21];
    __shared__ float qpart[2][8][64];
    __shared__ int   winsS[64];
    __shared__ float logps[64];
    __shared__ unsigned short lutI[496], lutJ[496];
    __shared__ float med2[4];                        // [state][2]
    __shared__ float qvS[64];
    __shared__ float normsS[64], diagS[64], rowKS[64];

    // hbuf alias map (short offsets), all lifetimes confined between "g1 dead" and "next h1":
    float* d2sF = (float*)hbuf;          // shorts     0.. 4095 : d2s fp32 [2][32][32]
    float* GSF  = ((float*)hbuf) + 2048; // shorts  4096.. 8191 : X@S^T fp32 [2][32][32]
    short* KbS  = hbuf + 8192;           // shorts  8192..10239 : K bf16 [2][32][32]
    short* SBs  = hbuf + 10240;          // shorts 10240..12287 : S bf16 [64][32] (k-pad 0)
    short* STbS = hbuf + 12288;          // shorts 12288..14335 : S^T bf16 [2][32dd][32j]
    short* XTbS = hbuf + 14336;          // shorts 14336..16383 : X^T bf16 [2][32dd][32j]

    const int t = threadIdx.x, b = blockIdx.x;
    const int lane = t & 63, wv = t >> 6;           // 8 waves
    const int q = lane >> 4, mp = lane & 15;
    const int nb = wv * 32;                          // 32-col slice of the 256-wide GEMMs

    // ---- init ----
    for (int p = t; p < 64*ODIM; p += 512) {
        int i = p >> 6, d = p & 63;
        A0s[i*96 + d] = f2bfT(obs[(b*64 + i)*ODIM + d]);
    }
    for (int p = t; p < 64*ADIM; p += 512) {
        int i = p / 20, d = p - i*20;
        float v = a0g[(b*64 + i)*20 + d];
        Xm[p] = v;
        A0s[i*96 + 64 + d] = f2bfT(v);
    }
    for (int p = t; p < 64*12; p += 512) { int i = p/12, d = p - i*12; A0s[i*96 + 84 + d] = 0; }
    { unsigned* mz = &maskS[0][0][0][0];
      for (int p = t; p < 2*2*64*8; p += 512) mz[p] = 0u; }
    if (t < 496) {
        int i_ = 0, rem = t;
        while (rem >= 31 - i_) { rem -= 31 - i_; ++i_; }
        lutI[t] = (unsigned short)i_; lutJ[t] = (unsigned short)(i_ + 1 + rem);
    }
    if (t < 64) logps[t] = 0.f;
    __syncthreads();

    for (int step = 0; step < NSTEPS; ++step) {
        // ================= forward both nets =================
        for (int net = 0; net < 2; ++net) {
            const unsigned short* w1t = ws + OW1T(net);
            const unsigned short* w2t = ws + OW2T(net);
            const float* b1p = net ? b1b : b1a;
            const float* b2p = net ? b2b : b2a;
            const float* w3p = net ? w3bf : w3af;

            // ---- L1: [64 x 96] @ w1t -> h1 ----
            f4 acc[4][2];
            #pragma unroll
            for (int h = 0; h < 4; ++h) { acc[h][0] = (f4){0,0,0,0}; acc[h][1] = (f4){0,0,0,0}; }
            {
                const unsigned short* bp0 = w1t + (size_t)(nb +      mp)*96 + q*8;
                const unsigned short* bp1 = w1t + (size_t)(nb + 16 + mp)*96 + q*8;
                bf8 bb0 = *(const bf8*)bp0, bb1 = *(const bf8*)bp1;
                #pragma unroll
                for (int k0 = 0; k0 < 96; k0 += 32) {
                    bf8 n0 = bb0, n1 = bb1;
                    if (k0 + 32 < 96) { n0 = *(const bf8*)(bp0 + k0 + 32); n1 = *(const bf8*)(bp1 + k0 + 32); }
                    #pragma unroll
                    for (int h = 0; h < 4; ++h) {
                        bf8 aa = *(const bf8*)&A0s[(h*16 + mp)*96 + k0 + q*8];
                        acc[h][0] = MFMA(aa, bb0, acc[h][0]);
                        acc[h][1] = MFMA(aa, bb1, acc[h][1]);
                    }
                    bb0 = n0; bb1 = n1;
                }
            }
            #pragma unroll
            for (int h = 0; h < 4; ++h) {
                #pragma unroll
                for (int s = 0; s < 2; ++s) {
                    int n0 = nb + s*16, col = n0 + mp;
                    float bias = b1p[col];
                    #pragma unroll
                    for (int r = 0; r < 4; ++r) {
                        float v = acc[h][s][r] + bias;
                        bool pos = v > 0.f;
                        unsigned long long bal = __ballot(pos);
                        hbuf[(h*16 + q*4 + r)*264 + col] = f2bfT(pos ? v : 0.f);
                        if (mp == 0)
                            atomicOr(&maskS[net][0][h*16 + q*4 + r][n0 >> 5],
                                     ((unsigned)((bal >> (q*16)) & 0xFFFFull)) << (n0 & 16));
                    }
                }
            }
            __syncthreads();

            // ---- L2: h1 @ w2t ----
            #pragma unroll
            for (int h = 0; h < 4; ++h) { acc[h][0] = (f4){0,0,0,0}; acc[h][1] = (f4){0,0,0,0}; }
            {
                const unsigned short* bp0 = w2t + (size_t)(nb +      mp)*256 + q*8;
                const unsigned short* bp1 = w2t + (size_t)(nb + 16 + mp)*256 + q*8;
                bf8 bb0 = *(const bf8*)bp0, bb1 = *(const bf8*)bp1;
                #pragma unroll
                for (int k0 = 0; k0 < 256; k0 += 32) {
                    bf8 n0 = bb0, n1 = bb1;
                    if (k0 + 32 < 256) { n0 = *(const bf8*)(bp0 + k0 + 32); n1 = *(const bf8*)(bp1 + k0 + 32); }
                    #pragma unroll
                    for (int h = 0; h < 4; ++h) {
                        bf8 aa = *(const bf8*)&hbuf[(h*16 + mp)*264 + k0 + q*8];
                        acc[h][0] = MFMA(aa, bb0, acc[h][0]);
                        acc[h][1] = MFMA(aa, bb1, acc[h][1]);
                    }
                    bb0 = n0; bb1 = n1;
                }
            }
            {
                float qp[4][4] = {{0,0,0,0},{0,0,0,0},{0,0,0,0},{0,0,0,0}};
                #pragma unroll
                for (int h = 0; h < 4; ++h) {
                    #pragma unroll
                    for (int s = 0; s < 2; ++s) {
                        int n0 = nb + s*16, col = n0 + mp;
                        float bias = b2p[col], w3v = w3p[col];
                        #pragma unroll
                        for (int r = 0; r < 4; ++r) {
                            float v = acc[h][s][r] + bias;
                            bool pos = v > 0.f;
                            unsigned long long bal = __ballot(pos);
                            if (mp == 0)
                                atomicOr(&maskS[net][1][h*16 + q*4 + r][n0 >> 5],
                                         ((unsigned)((bal >> (q*16)) & 0xFFFFull)) << (n0 & 16));
                            qp[h][r] += pos ? v * w3v : 0.f;
                        }
                    }
                }
                #pragma unroll
                for (int d = 1; d < 16; d <<= 1)
                    #pragma unroll
                    for (int h = 0; h < 4; ++h)
                        #pragma unroll
                        for (int r = 0; r < 4; ++r)
                            qp[h][r] += __shfl_xor(qp[h][r], d, 64);
                if (mp == 0) {
                    #pragma unroll
                    for (int h = 0; h < 4; ++h)
                        #pragma unroll
                        for (int r = 0; r < 4; ++r)
                            qpart[net][wv][h*16 + q*4 + r] = qp[h][r];
                }
            }
            __syncthreads();
        }

        // ======= argmin =======
        if (t < 64) {
            float q0 = b3a[0], q1 = b3b[0];
            #pragma unroll
            for (int w = 0; w < 8; ++w) { q0 += qpart[0][w][t]; q1 += qpart[1][w][t]; }
            winsS[t] = (q0 <= q1) ? 0 : 1;
        }
        __syncthreads();

        // ============ backward both nets + score ============
        for (int net = 0; net < 2; ++net) {
            const unsigned short* w2c  = ws + OW2C(net);
            const unsigned short* w3b8 = ws + OW3B(net);

            f4 acc[4][2];
            #pragma unroll
            for (int h = 0; h < 4; ++h) { acc[h][0] = (f4){0,0,0,0}; acc[h][1] = (f4){0,0,0,0}; }
            int win[4];
            #pragma unroll
            for (int h = 0; h < 4; ++h) win[h] = (winsS[h*16 + mp] == net);
            {
                const unsigned short* bp0 = w2c + (size_t)(nb +      mp)*256 + q*8;
                const unsigned short* bp1 = w2c + (size_t)(nb + 16 + mp)*256 + q*8;
                bf8 bb0 = *(const bf8*)bp0, bb1 = *(const bf8*)bp1;
                #pragma unroll
                for (int k0 = 0; k0 < 256; k0 += 32) {
                    bf8 n0 = bb0, n1 = bb1;
                    if (k0 + 32 < 256) { n0 = *(const bf8*)(bp0 + k0 + 32); n1 = *(const bf8*)(bp1 + k0 + 32); }
                    bf8 w3v = *(const bf8*)(w3b8 + k0 + q*8);
                    #pragma unroll
                    for (int h = 0; h < 4; ++h) {
                        unsigned bits = win[h] ? ((maskS[net][1][h*16 + mp][k0 >> 5] >> (q*8)) & 0xFFu) : 0u;
                        bf8 aa;
                        #pragma unroll
                        for (int j = 0; j < 8; ++j)
                            aa[j] = ((bits >> j) & 1u) ? w3v[j] : (short)0;
                        acc[h][0] = MFMA(aa, bb0, acc[h][0]);
                        acc[h][1] = MFMA(aa, bb1, acc[h][1]);
                    }
                    bb0 = n0; bb1 = n1;
                }
            }
            #pragma unroll
            for (int h = 0; h < 4; ++h) {
                #pragma unroll
                for (int s = 0; s < 2; ++s) {
                    int col = nb + s*16 + mp;
                    #pragma unroll
                    for (int r = 0; r < 4; ++r) {
                        int row = h*16 + q*4 + r;
                        bool on = (maskS[net][0][row][col >> 5] >> (col & 31)) & 1u;
                        hbuf[row*264 + col] = f2bfT(on ? acc[h][s][r] : 0.f);
                    }
                }
            }
            __syncthreads();
            // score: wave -> (m-tile, col-half)
            {
                int mt = wv & 3, ch = wv >> 2;
                const unsigned short* w1x = ws + OW1X(net);
                const unsigned short* bp  = w1x + (size_t)(ch*16 + mp)*256 + q*8;
                f4 sa = (f4){0,0,0,0};
                bf8 bx = *(const bf8*)bp;
                #pragma unroll
                for (int k0 = 0; k0 < 256; k0 += 32) {
                    bf8 nx = bx;
                    if (k0 + 32 < 256) nx = *(const bf8*)(bp + k0 + 32);
                    bf8 aa = *(const bf8*)&hbuf[(mt*16 + mp)*264 + k0 + q*8];
                    sa = MFMA(aa, bx, sa);
                    bx = nx;
                }
                int colD = ch*16 + mp;
                if (colD < 20) {
                    #pragma unroll
                    for (int r = 0; r < 4; ++r) {
                        int row = mt*16 + q*4 + r;
                        if (net == 0) scoreS[row*21 + colD]  = sa[r];
                        else          scoreS[row*21 + colD] += sa[r];
                    }
                }
            }
            __syncthreads();
        }

        // ================= RBF via MFMA =================
        // P1: shadows (S, S^T, X^T bf16), norms (from bf16 X), diag terms
        if (t < 64) {
            int st = t >> 5;
            float nrm = 0.f, dg = 0.f;
            #pragma unroll
            for (int d = 0; d < 20; ++d) {
                float xb = bf2f(A0s[t*96 + 64 + d]);
                nrm += xb * xb;
                float sv = scoreS[t*21 + d];
                float xv = Xm[t*20 + d];
                dg += xv * sv;
                short sb = f2bfT(sv);
                SBs[t*32 + d] = sb;
                STbS[st*1024 + d*32 + (t & 31)] = sb;
                XTbS[st*1024 + d*32 + (t & 31)] = f2bfT(xv);
            }
            #pragma unroll
            for (int d = 20; d < 32; ++d) SBs[t*32 + d] = 0;
            normsS[t] = nrm;
            diagS[t]  = dg;
        }
        __syncthreads();

        // P2: d2s = n_i + n_j - 2*(X X^T)_ij   and   GS = X S^T  (one tile per wave)
        {
            int stw = wv >> 2, mt = (wv >> 1) & 1, nt = wv & 1;
            bf8 aa  = *(const bf8*)&A0s[(stw*32 + mt*16 + mp)*96 + 64 + q*8];
            bf8 bbx = *(const bf8*)&A0s[(stw*32 + nt*16 + mp)*96 + 64 + q*8];
            bf8 bbs = *(const bf8*)&SBs[(stw*32 + nt*16 + mp)*32 + q*8];
            f4 gx = MFMA(aa, bbx, ((f4){0,0,0,0}));
            f4 gs = MFMA(aa, bbs, ((f4){0,0,0,0}));
            int jl = nt*16 + mp;
            float nj = normsS[stw*32 + jl];
            #pragma unroll
            for (int r = 0; r < 4; ++r) {
                int il = mt*16 + q*4 + r;
                d2sF[stw*1024 + il*32 + jl] = normsS[stw*32 + il] + nj - 2.f*gx[r];
                GSF [stw*1024 + il*32 + jl] = gs[r];
            }
        }
        __syncthreads();

        // P3: waves 0-1 sort for median; waves 2-7 zero masks for next step
        if (wv < 2) {
            const float* base = d2sF + wv*1024;
            float v[8];
            #pragma unroll
            for (int i = 0; i < 8; ++i) {
                int e = lane*8 + i;
                v[i] = (e < 496) ? base[lutI[e]*32 + lutJ[e]] : 3.4e38f;
            }
            for (int k = 2; k <= 512; k <<= 1) {
                for (int jj = k >> 1; jj >= 8; jj >>= 1) {
                    int lm = jj >> 3;
                    #pragma unroll
                    for (int i = 0; i < 8; ++i) {
                        float w = __shfl_xor(v[i], lm, 64);
                        int p = lane*8 + i;
                        bool takeMin = (((p & k) == 0) == ((p & jj) == 0));
                        v[i] = takeMin ? fminf(v[i], w) : fmaxf(v[i], w);
                    }
                }
                int jj0 = (k >> 1) < 4 ? (k >> 1) : 4;
                for (int jj = jj0; jj >= 1; jj >>= 1) {
                    #pragma unroll
                    for (int i = 0; i < 8; ++i) {
                        if ((i & jj) == 0) {
                            int i2 = i | jj;
                            int p = lane*8 + i;
                            bool up = ((p & k) == 0);
                            float x = v[i], y = v[i2];
                            float mn = fminf(x, y), mx = fmaxf(x, y);
                            v[i] = up ? mn : mx; v[i2] = up ? mx : mn;
                        }
                    }
                }
            }
            if (lane == 29) med2[wv*2 + 0] = v[7];   // sorted index 239
            if (lane == 30) med2[wv*2 + 1] = v[0];   // sorted index 240
        } else {
            unsigned* mz = &maskS[0][0][0][0];
            for (int p = t - 128; p < 2*2*64*8; p += 384) mz[p] = 0u;
        }
        __syncthreads();

        // P4: K = exp(-gamma d2s) -> Kb bf16; fused logp row-sums + rowK (8-lane shfl reduce)
        {
            int i = t >> 3, stw = i >> 5, il = i & 31, j0 = (t & 7) * 4;
            float medv = 0.5f * (med2[stw*2] + med2[stw*2 + 1]);
            float gam  = 1.f / (2.f * (medv / (2.f * LOG33)) + 1e-8f);
            float sK = 0.f, sKGS = 0.f, sKd2 = 0.f, sKdg = 0.f;
            #pragma unroll
            for (int jj = 0; jj < 4; ++jj) {
                int j = j0 + jj;
                float d2 = d2sF[stw*1024 + il*32 + j];
                float K  = expf(-gam * d2);
                KbS[stw*1024 + il*32 + j] = f2bfT(K);
                sK   += K;
                sKGS += K * GSF[stw*1024 + il*32 + j];
                sKd2 += K * d2;
                sKdg += K * diagS[stw*32 + j];
            }
            #pragma unroll
            for (int d = 1; d < 8; d <<= 1) {
                sK   += __shfl_xor(sK,   d, 64);
                sKGS += __shfl_xor(sKGS, d, 64);
                sKd2 += __shfl_xor(sKd2, d, 64);
                sKdg += __shfl_xor(sKdg, d, 64);
            }
            if ((t & 7) == 0) {
                rowKS[i] = sK;
                float sdots = sKGS - sKdg;                       // sum_j K*dots
                float ssum  = -2.f*gam*sdots
                              - 2.f*gam*(2.f*gam*sKd2 - 20.f*(sK - 1.f));
                logps[i] -= LRC * (ssum * (1.f/32.f));
            }
        }
        __syncthreads();

        // P5: phi = (K@S + 2g(x*rowK - K@X))/32 ; X += LR*phi  (one (m,n) tile per wave)
        {
            int stw = wv >> 2, mt = (wv >> 1) & 1, nt = wv & 1;
            float medv = 0.5f * (med2[stw*2] + med2[stw*2 + 1]);
            float gam  = 1.f / (2.f * (medv / (2.f * LOG33)) + 1e-8f);
            bf8 aa  = *(const bf8*)&KbS [stw*1024 + (mt*16 + mp)*32 + q*8];
            bf8 b1v = *(const bf8*)&STbS[stw*1024 + (nt*16 + mp)*32 + q*8];
            bf8 b2v = *(const bf8*)&XTbS[stw*1024 + (nt*16 + mp)*32 + q*8];
            f4 ks = MFMA(aa, b1v, ((f4){0,0,0,0}));
            f4 kx = MFMA(aa, b2v, ((f4){0,0,0,0}));
            int dd = nt*16 + mp;
            if (dd < 20) {
                #pragma unroll
                for (int r = 0; r < 4; ++r) {
                    int gi = stw*32 + mt*16 + q*4 + r;
                    float xi  = Xm[gi*20 + dd];
                    float phi = (ks[r] + 2.f*gam*(xi*rowKS[gi] - kx[r])) * (1.f/32.f);
                    float nx  = xi + LRC * phi;
                    Xm[gi*20 + dd] = nx;
                    A0s[gi*96 + 64 + dd] = f2bfT(nx);
                }
            }
        }
        __syncthreads();
    } // steps

    // ================= epilogue =================
    for (int p = t; p < 64*20; p += 512) {
        int i = p / 20, d = p - i*20;
        out[(b*64 + i)*20 + d] = tanhf(Xm[p]);
    }
    if (t < 64) {
        float lt = 0.f, s0 = 0.f;
        for (int d = 0; d < 20; ++d) {
            float a  = Xm[t*20 + d];
            float x  = -2.f * a;
            float sp = fmaxf(x, 0.f) + log1pf(expf(-fabsf(x)));
            lt -= 2.f * (0.69314718056f - a - sp);
            float v = a0g[(b*64 + t)*20 + d];
            s0 += v * v;
        }
        qvS[t] = -18.3787706641f - 0.5f*s0 + logps[t] + lt;
    }
    __syncthreads();
    if (t < 2) {
        float s = 0.f;
        for (int i = 0; i < 32; ++i) s += qvS[t*32 + i];
        out[1024*32*20 + b*2 + t] = s * (1.f/32.f);
    }
}

extern "C" void kernel_launch(void* const* d_in, const int* in_sizes, int n_in,
                              void* d_out, int out_size, void* d_ws, size_t ws_size,
                              hipStream_t stream) {
    unsigned short* ws = (unsigned short*)d_ws;
    prep_weights<<<(WS_ELEMS + 255)/256, 256, 0, stream>>>(
        (const float*)d_in[2],  (const float*)d_in[4],  (const float*)d_in[6],
        (const float*)d_in[8],  (const float*)d_in[10], (const float*)d_in[12], ws);
    svgd_main<<<NBLK, 512, 0, stream>>>(
        (const float*)d_in[0],  (const float*)d_in[1],
        (const float*)d_in[3],  (const float*)d_in[5],  (const float*)d_in[7],
        (const float*)d_in[9],  (const float*)d_in[11], (const float*)d_in[13],
        (const float*)d_in[6],  (const float*)d_in[12],
        ws, (float*)d_out);
}